// Round 17
// baseline (626.558 us; speedup 1.0000x reference)
//
#include <hip/hip_runtime.h>

#define T_  512
#define B_  256
#define F_  128
#define U_  128
#define G4_ 512
#define L2E 1.4426950408889634f
#define NBLK2 32                             // merged recurrent blocks (8 rows each)
#define ZSTR8 (16 * 512 * 8)                 // zx-bf16 dwords per timestep
#define ZB_BYTES ((size_t)T_ * B_ * G4_ * 2) // 134217728

using f32x4 = __attribute__((ext_vector_type(4))) float;
using s16x8 = __attribute__((ext_vector_type(8))) short;
using u32x4 = __attribute__((ext_vector_type(4))) unsigned int;

#if __has_builtin(__builtin_amdgcn_exp2f)
#define EXP2(x) __builtin_amdgcn_exp2f(x)    // bare v_exp_f32, no libcall
#else
#define EXP2(x) exp2f(x)
#endif

__device__ __forceinline__ unsigned fbits(float f) { return __builtin_bit_cast(unsigned, f); }
__device__ __forceinline__ float bitsf(unsigned u) { return __builtin_bit_cast(float, u); }

// pure-C RNE fp32->bf16 (verified since R1; NO inline asm)
__device__ __forceinline__ unsigned short f2bf(float f) {
  unsigned u = fbits(f);
  u += 0x7FFFu + ((u >> 16) & 1u);
  return (unsigned short)(u >> 16);
}
// hardware RNE pack — VALU/loaded values only (never on MFMA acc: R9 lesson)
__device__ __forceinline__ unsigned cvt_pk_bf16(float lo, float hi) {
  unsigned r;
  asm("v_cvt_pk_bf16_f32 %0, %1, %2" : "=v"(r) : "v"(lo), "v"(hi));
  return r;
}
__device__ __forceinline__ s16x8 pack8(f32x4 a, f32x4 b) {
  u32x4 w;
  w[0] = cvt_pk_bf16(a[0], a[1]);
  w[1] = cvt_pk_bf16(a[2], a[3]);
  w[2] = cvt_pk_bf16(b[0], b[1]);
  w[3] = cvt_pk_bf16(b[2], b[3]);
  return __builtin_bit_cast(s16x8, w);
}
// barrier waiting only on LDS ops — global loads/stores stay in flight
__device__ __forceinline__ void sync_lds() {
  asm volatile("s_waitcnt lgkmcnt(0)\n\ts_barrier" ::: "memory");
}

// ====== kernel 1 (VERBATIM R14): zx = bf16(X @ (Wx*scale)), perm-trunc pack ======
__global__ __launch_bounds__(512, 2)
void zxb_gemm_kernel(const float* __restrict__ X, const float* __restrict__ WX,
                     unsigned* __restrict__ ZB)
{
  const int tid  = threadIdx.x;
  const int w    = tid >> 6;
  const int lane = tid & 63;
  const int lr   = lane & 15;
  const int lk   = lane >> 4;

  s16x8 bWx[4][4];
#pragma unroll
  for (int g = 0; g < 4; ++g) {
    const float scl = (g == 3) ? 2.0f * L2E : L2E;   // u-gate carries tanh's 2x
    const int col = g * 128 + w * 16 + lr;
#pragma unroll
    for (int kc = 0; kc < 4; ++kc) {
      s16x8 wx;
#pragma unroll
      for (int e = 0; e < 8; ++e) {
        const int k = kc * 32 + lk * 8 + e;
        wx[e] = (short)f2bf(WX[k * G4_ + col] * scl);
      }
      bWx[g][kc] = wx;
    }
  }

  const int G0 = blockIdx.x * 16;
  const float* xp = X + (size_t)(G0 * 16 + lr) * F_ + lk * 8;
  unsigned*    zp = ZB + ((size_t)(G0 * 8 + w) * 64 + lane) * 8;

  for (int grp = 0; grp < 16; ++grp) {
    s16x8 xa[4];
#pragma unroll
    for (int kc = 0; kc < 4; ++kc)
      xa[kc] = pack8(*(const f32x4*)(xp + kc * 32), *(const f32x4*)(xp + kc * 32 + 4));
#pragma unroll
    for (int g = 0; g < 4; ++g) {
      f32x4 a = {0.f, 0.f, 0.f, 0.f};
#pragma unroll
      for (int kc = 0; kc < 4; ++kc)
        a = __builtin_amdgcn_mfma_f32_16x16x32_bf16(xa[kc], bWx[g][kc], a, 0, 0, 0);
      const unsigned p0 = __builtin_amdgcn_perm(fbits(a[1]), fbits(a[0]), 0x07060302u);
      const unsigned p1 = __builtin_amdgcn_perm(fbits(a[3]), fbits(a[2]), 0x07060302u);
      zp[g * 2]     = p0;
      zp[g * 2 + 1] = p1;
    }
    xp += 16 * F_;
    zp += 8 * 64 * 8;
  }
}

// ====== kernel 2: R14 step body VERBATIM; 32 blocks x 1024 threads = two
//        independent 4-row half-blocks per block -> 4 waves/SIMD latency hiding ======
__global__ __launch_bounds__(1024, 1)
void lstm_zxb8_kernel(const unsigned* __restrict__ ZB, const float* __restrict__ ST,
                      const float* __restrict__ DN, const float* __restrict__ WH,
                      float* __restrict__ OUT)
{
  __shared__ __align__(16) short hbuf[2][2][4 * U_];   // [buf][half][row*U]

  const int tid  = threadIdx.x;
  const int w16  = tid >> 6;           // wave 0..15
  const int half = w16 >> 3;           // half-block 0/1
  const int w    = w16 & 7;            // wave within half 0..7
  const int lane = tid & 63;
  const int lr   = lane & 15;
  const int lk   = lane >> 4;
  const int rl   = lk;                 // owned real row 0..3
  const int rr   = lr & 3;             // A-fragment source row (real)
  const int obx  = (int)blockIdx.x * 2 + half;   // equivalent R12/R14 block id 0..63
  const int b0   = obx * 4;
  const int uu   = w * 16 + lr;

  const int doff1 = b0 + rl;                 // this lane's done
  const int ooff1 = (b0 + rl) * U_ + uu;     // this lane's OUT row

  // publish address (shorts): row rl, slot (uu>>3)^(rl<<2), elem uu&7
  const int hP = rl * U_ + (((uu >> 3) ^ (rl << 2)) * 8) + (uu & 7);

  // Wh, pre-scaled per gate (log2e; 2*log2e for u)
  s16x8 bWh[4][4];
#pragma unroll
  for (int g = 0; g < 4; ++g) {
    const float scl = (g == 3) ? 2.0f * L2E : L2E;
    const int col = g * 128 + uu;
#pragma unroll
    for (int kc = 0; kc < 4; ++kc) {
      s16x8 wh;
#pragma unroll
      for (int e = 0; e < 8; ++e) {
        const int k = kc * 32 + lk * 8 + e;
        wh[e] = (short)f2bf(WH[k * G4_ + col] * scl);
      }
      bWh[g][kc] = wh;
    }
  }

  // fp32 state: 1 row per lane
  float c  = ST[doff1 * U_ + uu];
  float hn = ST[(B_ + doff1) * U_ + uu];
  { // mask m(0), publish (single write; mirrors read-side broadcast)
    const float m = 1.0f - DN[doff1];
    c *= m;
    hbuf[0][half][hP] = (short)f2bf(hn * m);
  }

  // zx thread-const dword offset (R11-verified remap, via equivalent block id)
  const int zoff = (((obx >> 2) * 8 + w) * 64 + (obx & 3) * 16 + lr) * 8;

  u32x4 zA0, zA1, zB0, zB1;
  float dv;
  zA0 = *(const u32x4*)(ZB + zoff);
  zA1 = *(const u32x4*)(ZB + zoff + 4);
  zB0 = *(const u32x4*)(ZB + ZSTR8 + zoff);
  zB1 = *(const u32x4*)(ZB + ZSTR8 + zoff + 4);
  dv = DN[B_ + doff1];
  sync_lds();  // h(0) visible

  // step: tz/td/to are loop-uniform element offsets (SGPR-side stepping)
  auto step = [&](const int p, const bool pub, const bool pre,
                  u32x4& zq0, u32x4& zq1, const int tz, const int td, const int to) {
    // a) h(t) A-fragments: read real row rr, slot (kc*4+lk)^(rr<<2) — 4x broadcast
    s16x8 ah[4];
#pragma unroll
    for (int kc = 0; kc < 4; ++kc) {
      const int sl = (kc * 4 + lk) ^ (rr << 2);
      ah[kc] = *(const s16x8*)&hbuf[p][half][rr * U_ + sl * 8];
    }
    // b) decode bf16 zx -> f32 C-init, z = zx + h @ Wh
    f32x4 az[4];
#pragma unroll
    for (int g = 0; g < 4; ++g) {
      const unsigned d0 = (g < 2) ? zq0[(g & 1) * 2]     : zq1[(g & 1) * 2];
      const unsigned d1 = (g < 2) ? zq0[(g & 1) * 2 + 1] : zq1[(g & 1) * 2 + 1];
      f32x4 a = { bitsf(d0 << 16), bitsf(d0 & 0xFFFF0000u),
                  bitsf(d1 << 16), bitsf(d1 & 0xFFFF0000u) };
#pragma unroll
      for (int kc = 0; kc < 4; ++kc)
        a = __builtin_amdgcn_mfma_f32_16x16x32_bf16(ah[kc], bWh[g][kc], a, 0, 0, 0);
      az[g] = a;
    }
    // c) refill zx(t+2) — uniform base + const voffset (after C-init consumed)
    if (pre) {
      zq0 = *(const u32x4*)(ZB + tz + zoff);
      zq1 = *(const u32x4*)(ZB + tz + zoff + 4);
    }
    // d) activation for this lane's SINGLE row (r = lk)
    {
      const float z0 = az[0][rl];
      const float z1 = az[1][rl];
      const float z2 = az[2][rl];
      const float z3 = az[3][rl];
      const float eA = EXP2(-z0);
      const float eC = EXP2(-z1);
      const float eD = EXP2(-z2);
      const float eB = EXP2(-z3);
      const float iu = (1.0f - eB) * __builtin_amdgcn_rcpf((1.0f + eA) * (1.0f + eB));
      const float fg = __builtin_amdgcn_rcpf(1.0f + eC);
      const float cn = fmaf(fg, c, iu);
      const float ce = fminf(fmaxf(cn, -15.0f), 15.0f);
      const float eE = EXP2(ce * (-2.0f * L2E));
      const float h  = (1.0f - eE) * __builtin_amdgcn_rcpf((1.0f + eD) * (1.0f + eE));
      c  = cn;
      hn = h;
      OUT[to + ooff1] = h;
    }
    // e) done for t+1 (held), issue d(t+2)
    const float dcur = dv;
    if (pre) dv = DN[td + doff1];
    // f) mask m(t+1), publish single short
    if (pub) {
      const float m = 1.0f - dcur;
      c *= m;
      hbuf[p ^ 1][half][hP] = (short)f2bf(hn * m);
    }
    sync_lds();
  };

  for (int t = 0; t < T_; t += 2) {
    step(0, true, t + 2 < T_, zA0, zA1,
         (t + 2) * ZSTR8, (t + 2) * B_, t * (B_ * U_));
    step(1, t + 2 < T_, t + 3 < T_, zB0, zB1,
         (t + 3) * ZSTR8, (t + 3) * B_, (t + 1) * (B_ * U_));
  }

  // final carry (c, h) after step T-1, unmasked — 1 row per lane
  const long fb = (long)T_ * B_ * U_;
  OUT[fb + (long)doff1 * U_ + uu]                 = c;
  OUT[fb + (long)B_ * U_ + (long)doff1 * U_ + uu] = hn;
}

// ============ fallback (R3 kernel verbatim): used when ws is too small ============
__global__ __launch_bounds__(512, 1)
void lstm_fb_kernel(const float* __restrict__ X, const float* __restrict__ ST,
                    const float* __restrict__ DN, const float* __restrict__ WX,
                    const float* __restrict__ WH, float* __restrict__ OUT)
{
  __shared__ __align__(16) short hbuf[2][16 * U_];

  const int tid  = threadIdx.x;
  const int w    = tid >> 6;
  const int lane = tid & 63;
  const int lr   = lane & 15;
  const int lk   = lane >> 4;
  const int b0   = blockIdx.x * 16;
  const int row0 = lk * 4;
  const int uu   = w * 16 + lr;

  const int xoff = (b0 + lr) * F_ + lk * 8;
  const int doff = b0 + row0;
  const int ooff = (b0 + row0) * U_ + uu;

  s16x8 bWh[4][4], bWx[4][4];
#pragma unroll
  for (int g = 0; g < 4; ++g) {
    const int col = g * 128 + uu;
#pragma unroll
    for (int kc = 0; kc < 4; ++kc) {
      s16x8 wh, wx;
#pragma unroll
      for (int e = 0; e < 8; ++e) {
        const int k = kc * 32 + lk * 8 + e;
        wh[e] = (short)f2bf(WH[k * G4_ + col]);
        wx[e] = (short)f2bf(WX[k * G4_ + col]);
      }
      bWh[g][kc] = wh;
      bWx[g][kc] = wx;
    }
  }

  float c[4], hn[4];
#pragma unroll
  for (int r = 0; r < 4; ++r) {
    c[r]  = ST[(b0 + row0 + r) * U_ + uu];
    hn[r] = ST[(B_ + b0 + row0 + r) * U_ + uu];
  }
  {
    f32x4 d = *(const f32x4*)&DN[doff];
#pragma unroll
    for (int r = 0; r < 4; ++r) {
      const float m = 1.0f - d[r];
      c[r] *= m;
      const int row = row0 + r;
      const int sl  = (uu >> 3) ^ row;
      hbuf[0][row * U_ + sl * 8 + (uu & 7)] = (short)cvt_pk_bf16(hn[r] * m, 0.f);
    }
  }

  f32x4 xv0[4], xv1[4], dv;
  f32x4 accA[4], accB[4];
  {
    const float* xp = X + xoff;
    s16x8 xa[4];
#pragma unroll
    for (int kc = 0; kc < 4; ++kc)
      xa[kc] = pack8(*(const f32x4*)(xp + kc * 32), *(const f32x4*)(xp + kc * 32 + 4));
#pragma unroll
    for (int g = 0; g < 4; ++g) {
      f32x4 a = {0.f, 0.f, 0.f, 0.f};
#pragma unroll
      for (int kc = 0; kc < 4; ++kc)
        a = __builtin_amdgcn_mfma_f32_16x16x32_bf16(xa[kc], bWx[g][kc], a, 0, 0, 0);
      accA[g] = a;
    }
#pragma unroll
    for (int kc = 0; kc < 4; ++kc) {
      xv0[kc] = *(const f32x4*)(X + B_ * F_ + xoff + kc * 32);
      xv1[kc] = *(const f32x4*)(X + B_ * F_ + xoff + kc * 32 + 4);
    }
    dv = *(const f32x4*)(DN + B_ + doff);
  }
  sync_lds();

  const float* Xt  = X + 2 * B_ * F_;
  const float* DNt = DN + 2 * B_;
  float*       Ot  = OUT;

  auto step = [&](const int p, const bool act_x, const bool pre_x,
                  f32x4 (&accZ)[4], f32x4 (&accX)[4]) {
    s16x8 ah[4];
#pragma unroll
    for (int kc = 0; kc < 4; ++kc) {
      const int sl = (kc * 4 + lk) ^ lr;
      ah[kc] = *(const s16x8*)&hbuf[p][lr * U_ + sl * 8];
    }
#pragma unroll
    for (int g = 0; g < 4; ++g) {
      f32x4 a = accZ[g];
#pragma unroll
      for (int kc = 0; kc < 4; ++kc)
        a = __builtin_amdgcn_mfma_f32_16x16x32_bf16(ah[kc], bWh[g][kc], a, 0, 0, 0);
      accZ[g] = a;
    }
#pragma unroll
    for (int r = 0; r < 4; ++r) {
      const float eA = __expf(-accZ[0][r]);
      const float eB = __expf(-2.0f * accZ[3][r]);
      const float eC = __expf(-accZ[1][r]);
      const float eD = __expf(-accZ[2][r]);
      const float iu = (1.0f - eB) * __builtin_amdgcn_rcpf((1.0f + eA) * (1.0f + eB));
      const float fg = __builtin_amdgcn_rcpf(1.0f + eC);
      const float cn = fmaf(fg, c[r], iu);
      const float ce = fminf(fmaxf(cn, -30.0f), 30.0f);
      const float eE = __expf(-2.0f * ce);
      const float h  = (1.0f - eE) * __builtin_amdgcn_rcpf((1.0f + eD) * (1.0f + eE));
      c[r]  = cn;
      hn[r] = h;
      Ot[ooff + r * U_] = h;
    }
    if (act_x) {
      s16x8 xa[4];
#pragma unroll
      for (int kc = 0; kc < 4; ++kc) xa[kc] = pack8(xv0[kc], xv1[kc]);
#pragma unroll
      for (int g = 0; g < 4; ++g) {
        f32x4 a = {0.f, 0.f, 0.f, 0.f};
#pragma unroll
        for (int kc = 0; kc < 4; ++kc)
          a = __builtin_amdgcn_mfma_f32_16x16x32_bf16(xa[kc], bWx[g][kc], a, 0, 0, 0);
        accX[g] = a;
      }
    }
    f32x4 dcur = dv;
    if (pre_x) {
#pragma unroll
      for (int kc = 0; kc < 4; ++kc) {
        xv0[kc] = *(const f32x4*)(Xt + xoff + kc * 32);
        xv1[kc] = *(const f32x4*)(Xt + xoff + kc * 32 + 4);
      }
      dv = *(const f32x4*)(DNt + doff);
    }
    if (act_x) {
#pragma unroll
      for (int r = 0; r < 4; ++r) {
        const float m = 1.0f - dcur[r];
        c[r] *= m;
        const int row = row0 + r;
        const int sl  = (uu >> 3) ^ row;
        hbuf[p ^ 1][row * U_ + sl * 8 + (uu & 7)] = (short)cvt_pk_bf16(hn[r] * m, 0.f);
      }
    }
    sync_lds();
  };

  for (int t = 0; t < T_; t += 2) {
    step(0, true, t + 2 < T_, accA, accB);
    Xt += B_ * F_; DNt += B_; Ot += B_ * U_;
    step(1, t + 2 < T_, t + 3 < T_, accB, accA);
    Xt += B_ * F_; DNt += B_; Ot += B_ * U_;
  }

  const long fb = (long)T_ * B_ * U_;
#pragma unroll
  for (int r = 0; r < 4; ++r) {
    OUT[fb + (long)(b0 + row0 + r) * U_ + uu]                 = c[r];
    OUT[fb + (long)B_ * U_ + (long)(b0 + row0 + r) * U_ + uu] = hn[r];
  }
}

extern "C" void kernel_launch(void* const* d_in, const int* in_sizes, int n_in,
                              void* d_out, int out_size, void* d_ws, size_t ws_size,
                              hipStream_t stream) {
  const float* X  = (const float*)d_in[0];  // [T,B,F]
  const float* ST = (const float*)d_in[1];  // [2,B,U]
  const float* DN = (const float*)d_in[2];  // [T,B]
  const float* WX = (const float*)d_in[3];  // [F,4U]
  const float* WH = (const float*)d_in[4];  // [U,4U]
  float* OUT = (float*)d_out;               // [T*B*U + 2*B*U]

  if (ws_size >= ZB_BYTES) {
    unsigned* ZB = (unsigned*)d_ws;
    zxb_gemm_kernel<<<dim3(512), dim3(512), 0, stream>>>(X, WX, ZB);
    lstm_zxb8_kernel<<<dim3(NBLK2), dim3(1024), 0, stream>>>(ZB, ST, DN, WH, OUT);
  } else {
    lstm_fb_kernel<<<dim3(16), dim3(512), 0, stream>>>(X, ST, DN, WX, WH, OUT);
  }
}

// Round 18
// 406.490 us; speedup vs baseline: 1.5414x; 1.5414x over previous
//
#include <hip/hip_runtime.h>

#define T_  512
#define B_  256
#define F_  128
#define U_  128
#define G4_ 512
#define L2E 1.4426950408889634f
#define NBLK 64                              // recurrent blocks (4 real rows each)
#define ZSTR8 (16 * 512 * 8)                 // zx-bf16 dwords per timestep
#define ZB_BYTES ((size_t)T_ * B_ * G4_ * 2) // 134217728

using f32x4 = __attribute__((ext_vector_type(4))) float;
using s16x8 = __attribute__((ext_vector_type(8))) short;
using u32x4 = __attribute__((ext_vector_type(4))) unsigned int;

#if __has_builtin(__builtin_amdgcn_exp2f)
#define EXP2(x) __builtin_amdgcn_exp2f(x)    // bare v_exp_f32, no libcall
#else
#define EXP2(x) exp2f(x)
#endif

__device__ __forceinline__ unsigned fbits(float f) { return __builtin_bit_cast(unsigned, f); }
__device__ __forceinline__ float bitsf(unsigned u) { return __builtin_bit_cast(float, u); }

// pure-C RNE fp32->bf16 (verified since R1; NO inline asm)
__device__ __forceinline__ unsigned short f2bf(float f) {
  unsigned u = fbits(f);
  u += 0x7FFFu + ((u >> 16) & 1u);
  return (unsigned short)(u >> 16);
}
// hardware RNE pack — VALU/loaded values only (never on MFMA acc: R9 lesson)
__device__ __forceinline__ unsigned cvt_pk_bf16(float lo, float hi) {
  unsigned r;
  asm("v_cvt_pk_bf16_f32 %0, %1, %2" : "=v"(r) : "v"(lo), "v"(hi));
  return r;
}
__device__ __forceinline__ s16x8 pack8(f32x4 a, f32x4 b) {
  u32x4 w;
  w[0] = cvt_pk_bf16(a[0], a[1]);
  w[1] = cvt_pk_bf16(a[2], a[3]);
  w[2] = cvt_pk_bf16(b[0], b[1]);
  w[3] = cvt_pk_bf16(b[2], b[3]);
  return __builtin_bit_cast(s16x8, w);
}
// barrier waiting only on LDS ops — global loads/stores stay in flight
__device__ __forceinline__ void sync_lds() {
  asm volatile("s_waitcnt lgkmcnt(0)\n\ts_barrier" ::: "memory");
}

// ====== kernel 1 (VERBATIM R12, best-measured): zx = bf16(X @ (Wx*scale)) ======
__global__ __launch_bounds__(512, 2)
void zxb_gemm_kernel(const float* __restrict__ X, const float* __restrict__ WX,
                     unsigned* __restrict__ ZB)
{
  const int tid  = threadIdx.x;
  const int w    = tid >> 6;
  const int lane = tid & 63;
  const int lr   = lane & 15;
  const int lk   = lane >> 4;

  s16x8 bWx[4][4];
#pragma unroll
  for (int g = 0; g < 4; ++g) {
    const float scl = (g == 3) ? 2.0f * L2E : L2E;   // u-gate carries tanh's 2x
    const int col = g * 128 + w * 16 + lr;
#pragma unroll
    for (int kc = 0; kc < 4; ++kc) {
      s16x8 wx;
#pragma unroll
      for (int e = 0; e < 8; ++e) {
        const int k = kc * 32 + lk * 8 + e;
        wx[e] = (short)f2bf(WX[k * G4_ + col] * scl);
      }
      bWx[g][kc] = wx;
    }
  }

  const int G0 = blockIdx.x * 16;
  const float* xp = X + (size_t)(G0 * 16 + lr) * F_ + lk * 8;
  unsigned*    zp = ZB + ((size_t)(G0 * 8 + w) * 64 + lane) * 8;

  for (int grp = 0; grp < 16; ++grp) {
    s16x8 xa[4];
#pragma unroll
    for (int kc = 0; kc < 4; ++kc)
      xa[kc] = pack8(*(const f32x4*)(xp + kc * 32), *(const f32x4*)(xp + kc * 32 + 4));
#pragma unroll
    for (int g = 0; g < 4; ++g) {
      f32x4 a = {0.f, 0.f, 0.f, 0.f};
#pragma unroll
      for (int kc = 0; kc < 4; ++kc)
        a = __builtin_amdgcn_mfma_f32_16x16x32_bf16(xa[kc], bWx[g][kc], a, 0, 0, 0);
      // pure-C RNE pack of the acc, stored immediately (R10-verified)
      const unsigned p0 = ((unsigned)f2bf(a[1]) << 16) | (unsigned)f2bf(a[0]);
      const unsigned p1 = ((unsigned)f2bf(a[3]) << 16) | (unsigned)f2bf(a[2]);
      zp[g * 2]     = p0;
      zp[g * 2 + 1] = p1;
    }
    xp += 16 * F_;
    zp += 8 * 64 * 8;
  }
}

// ====== kernel 2 (VERBATIM R12): 64 blocks x 4 real rows; broadcast h-tile ======
__global__ __launch_bounds__(512, 1)
void lstm_zxb4_kernel(const unsigned* __restrict__ ZB, const float* __restrict__ ST,
                      const float* __restrict__ DN, const float* __restrict__ WH,
                      float* __restrict__ OUT)
{
  __shared__ __align__(16) short hbuf[2][4 * U_];   // 1 KB per buffer

  const int tid  = threadIdx.x;
  const int w    = tid >> 6;
  const int lane = tid & 63;
  const int lr   = lane & 15;
  const int lk   = lane >> 4;
  const int rl   = lk;                 // owned real row 0..3
  const int rr   = lr & 3;             // A-fragment source row (real)
  const int b0   = blockIdx.x * 4;
  const int uu   = w * 16 + lr;

  const int doff1 = b0 + rl;                 // this lane's done
  const int ooff1 = (b0 + rl) * U_ + uu;     // this lane's OUT row

  // publish address (shorts), thread-constant: row rl, slot (uu>>3)^(rl<<2), elem uu&7
  const int hP = rl * U_ + (((uu >> 3) ^ (rl << 2)) * 8) + (uu & 7);

  // Wh, pre-scaled per gate (log2e; 2*log2e for u)
  s16x8 bWh[4][4];
#pragma unroll
  for (int g = 0; g < 4; ++g) {
    const float scl = (g == 3) ? 2.0f * L2E : L2E;
    const int col = g * 128 + uu;
#pragma unroll
    for (int kc = 0; kc < 4; ++kc) {
      s16x8 wh;
#pragma unroll
      for (int e = 0; e < 8; ++e) {
        const int k = kc * 32 + lk * 8 + e;
        wh[e] = (short)f2bf(WH[k * G4_ + col] * scl);
      }
      bWh[g][kc] = wh;
    }
  }

  // fp32 state: 1 row per lane
  float c  = ST[doff1 * U_ + uu];
  float hn = ST[(B_ + doff1) * U_ + uu];
  { // mask m(0), publish (single write; mirrors read-side broadcast)
    const float m = 1.0f - DN[doff1];
    c *= m;
    hbuf[0][hP] = (short)f2bf(hn * m);
  }

  // zx thread-const dword offset (R11-verified remap)
  const int zoff = ((((int)blockIdx.x >> 2) * 8 + w) * 64 + ((int)blockIdx.x & 3) * 16 + lr) * 8;

  u32x4 zA0, zA1, zB0, zB1;
  float dv;
  zA0 = *(const u32x4*)(ZB + zoff);
  zA1 = *(const u32x4*)(ZB + zoff + 4);
  zB0 = *(const u32x4*)(ZB + ZSTR8 + zoff);
  zB1 = *(const u32x4*)(ZB + ZSTR8 + zoff + 4);
  dv = DN[B_ + doff1];
  sync_lds();  // h(0) visible

  // step: tz/td/to are loop-uniform element offsets (SGPR-side stepping)
  auto step = [&](const int p, const bool pub, const bool pre,
                  u32x4& zq0, u32x4& zq1, const int tz, const int td, const int to) {
    // a) h(t) A-fragments: read real row rr, slot (kc*4+lk)^(rr<<2) — 4x broadcast
    s16x8 ah[4];
#pragma unroll
    for (int kc = 0; kc < 4; ++kc) {
      const int sl = (kc * 4 + lk) ^ (rr << 2);
      ah[kc] = *(const s16x8*)&hbuf[p][rr * U_ + sl * 8];
    }
    // b) decode bf16 zx -> f32 C-init, z = zx + h @ Wh
    f32x4 az[4];
#pragma unroll
    for (int g = 0; g < 4; ++g) {
      const unsigned d0 = (g < 2) ? zq0[(g & 1) * 2]     : zq1[(g & 1) * 2];
      const unsigned d1 = (g < 2) ? zq0[(g & 1) * 2 + 1] : zq1[(g & 1) * 2 + 1];
      f32x4 a = { bitsf(d0 << 16), bitsf(d0 & 0xFFFF0000u),
                  bitsf(d1 << 16), bitsf(d1 & 0xFFFF0000u) };
#pragma unroll
      for (int kc = 0; kc < 4; ++kc)
        a = __builtin_amdgcn_mfma_f32_16x16x32_bf16(ah[kc], bWh[g][kc], a, 0, 0, 0);
      az[g] = a;
    }
    // c) refill zx(t+2) — uniform base + const voffset
    if (pre) {
      zq0 = *(const u32x4*)(ZB + tz + zoff);
      zq1 = *(const u32x4*)(ZB + tz + zoff + 4);
    }
    // d) activation for this lane's SINGLE row (r = lk)
    {
      const float z0 = az[0][rl];
      const float z1 = az[1][rl];
      const float z2 = az[2][rl];
      const float z3 = az[3][rl];
      const float eA = EXP2(-z0);
      const float eC = EXP2(-z1);
      const float eD = EXP2(-z2);
      const float eB = EXP2(-z3);
      const float iu = (1.0f - eB) * __builtin_amdgcn_rcpf((1.0f + eA) * (1.0f + eB));
      const float fg = __builtin_amdgcn_rcpf(1.0f + eC);
      const float cn = fmaf(fg, c, iu);
      const float ce = fminf(fmaxf(cn, -15.0f), 15.0f);
      const float eE = EXP2(ce * (-2.0f * L2E));
      const float h  = (1.0f - eE) * __builtin_amdgcn_rcpf((1.0f + eD) * (1.0f + eE));
      c  = cn;
      hn = h;
      OUT[to + ooff1] = h;
    }
    // e) done for t+1 (held), issue d(t+2)
    const float dcur = dv;
    if (pre) dv = DN[td + doff1];
    // f) mask m(t+1), publish single short
    if (pub) {
      const float m = 1.0f - dcur;
      c *= m;
      hbuf[p ^ 1][hP] = (short)f2bf(hn * m);
    }
    sync_lds();
  };

  for (int t = 0; t < T_; t += 2) {
    step(0, true, t + 2 < T_, zA0, zA1,
         (t + 2) * ZSTR8, (t + 2) * B_, t * (B_ * U_));
    step(1, t + 2 < T_, t + 3 < T_, zB0, zB1,
         (t + 3) * ZSTR8, (t + 3) * B_, (t + 1) * (B_ * U_));
  }

  // final carry (c, h) after step T-1, unmasked — 1 row per lane
  const long fb = (long)T_ * B_ * U_;
  OUT[fb + (long)doff1 * U_ + uu]                 = c;
  OUT[fb + (long)B_ * U_ + (long)doff1 * U_ + uu] = hn;
}

// ============ fallback (R3 kernel verbatim): used when ws is too small ============
__global__ __launch_bounds__(512, 1)
void lstm_fb_kernel(const float* __restrict__ X, const float* __restrict__ ST,
                    const float* __restrict__ DN, const float* __restrict__ WX,
                    const float* __restrict__ WH, float* __restrict__ OUT)
{
  __shared__ __align__(16) short hbuf[2][16 * U_];

  const int tid  = threadIdx.x;
  const int w    = tid >> 6;
  const int lane = tid & 63;
  const int lr   = lane & 15;
  const int lk   = lane >> 4;
  const int b0   = blockIdx.x * 16;
  const int row0 = lk * 4;
  const int uu   = w * 16 + lr;

  const int xoff = (b0 + lr) * F_ + lk * 8;
  const int doff = b0 + row0;
  const int ooff = (b0 + row0) * U_ + uu;

  s16x8 bWh[4][4], bWx[4][4];
#pragma unroll
  for (int g = 0; g < 4; ++g) {
    const int col = g * 128 + uu;
#pragma unroll
    for (int kc = 0; kc < 4; ++kc) {
      s16x8 wh, wx;
#pragma unroll
      for (int e = 0; e < 8; ++e) {
        const int k = kc * 32 + lk * 8 + e;
        wh[e] = (short)f2bf(WH[k * G4_ + col]);
        wx[e] = (short)f2bf(WX[k * G4_ + col]);
      }
      bWh[g][kc] = wh;
      bWx[g][kc] = wx;
    }
  }

  float c[4], hn[4];
#pragma unroll
  for (int r = 0; r < 4; ++r) {
    c[r]  = ST[(b0 + row0 + r) * U_ + uu];
    hn[r] = ST[(B_ + b0 + row0 + r) * U_ + uu];
  }
  {
    f32x4 d = *(const f32x4*)&DN[doff];
#pragma unroll
    for (int r = 0; r < 4; ++r) {
      const float m = 1.0f - d[r];
      c[r] *= m;
      const int row = row0 + r;
      const int sl  = (uu >> 3) ^ row;
      hbuf[0][row * U_ + sl * 8 + (uu & 7)] = (short)cvt_pk_bf16(hn[r] * m, 0.f);
    }
  }

  f32x4 xv0[4], xv1[4], dv;
  f32x4 accA[4], accB[4];
  {
    const float* xp = X + xoff;
    s16x8 xa[4];
#pragma unroll
    for (int kc = 0; kc < 4; ++kc)
      xa[kc] = pack8(*(const f32x4*)(xp + kc * 32), *(const f32x4*)(xp + kc * 32 + 4));
#pragma unroll
    for (int g = 0; g < 4; ++g) {
      f32x4 a = {0.f, 0.f, 0.f, 0.f};
#pragma unroll
      for (int kc = 0; kc < 4; ++kc)
        a = __builtin_amdgcn_mfma_f32_16x16x32_bf16(xa[kc], bWx[g][kc], a, 0, 0, 0);
      accA[g] = a;
    }
#pragma unroll
    for (int kc = 0; kc < 4; ++kc) {
      xv0[kc] = *(const f32x4*)(X + B_ * F_ + xoff + kc * 32);
      xv1[kc] = *(const f32x4*)(X + B_ * F_ + xoff + kc * 32 + 4);
    }
    dv = *(const f32x4*)(DN + B_ + doff);
  }
  sync_lds();

  const float* Xt  = X + 2 * B_ * F_;
  const float* DNt = DN + 2 * B_;
  float*       Ot  = OUT;

  auto step = [&](const int p, const bool act_x, const bool pre_x,
                  f32x4 (&accZ)[4], f32x4 (&accX)[4]) {
    s16x8 ah[4];
#pragma unroll
    for (int kc = 0; kc < 4; ++kc) {
      const int sl = (kc * 4 + lk) ^ lr;
      ah[kc] = *(const s16x8*)&hbuf[p][lr * U_ + sl * 8];
    }
#pragma unroll
    for (int g = 0; g < 4; ++g) {
      f32x4 a = accZ[g];
#pragma unroll
      for (int kc = 0; kc < 4; ++kc)
        a = __builtin_amdgcn_mfma_f32_16x16x32_bf16(ah[kc], bWh[g][kc], a, 0, 0, 0);
      accZ[g] = a;
    }
#pragma unroll
    for (int r = 0; r < 4; ++r) {
      const float eA = __expf(-accZ[0][r]);
      const float eB = __expf(-2.0f * accZ[3][r]);
      const float eC = __expf(-accZ[1][r]);
      const float eD = __expf(-accZ[2][r]);
      const float iu = (1.0f - eB) * __builtin_amdgcn_rcpf((1.0f + eA) * (1.0f + eB));
      const float fg = __builtin_amdgcn_rcpf(1.0f + eC);
      const float cn = fmaf(fg, c[r], iu);
      const float ce = fminf(fmaxf(cn, -30.0f), 30.0f);
      const float eE = __expf(-2.0f * ce);
      const float h  = (1.0f - eE) * __builtin_amdgcn_rcpf((1.0f + eD) * (1.0f + eE));
      c[r]  = cn;
      hn[r] = h;
      Ot[ooff + r * U_] = h;
    }
    if (act_x) {
      s16x8 xa[4];
#pragma unroll
      for (int kc = 0; kc < 4; ++kc) xa[kc] = pack8(xv0[kc], xv1[kc]);
#pragma unroll
      for (int g = 0; g < 4; ++g) {
        f32x4 a = {0.f, 0.f, 0.f, 0.f};
#pragma unroll
        for (int kc = 0; kc < 4; ++kc)
          a = __builtin_amdgcn_mfma_f32_16x16x32_bf16(xa[kc], bWx[g][kc], a, 0, 0, 0);
        accX[g] = a;
      }
    }
    f32x4 dcur = dv;
    if (pre_x) {
#pragma unroll
      for (int kc = 0; kc < 4; ++kc) {
        xv0[kc] = *(const f32x4*)(Xt + xoff + kc * 32);
        xv1[kc] = *(const f32x4*)(Xt + xoff + kc * 32 + 4);
      }
      dv = *(const f32x4*)(DNt + doff);
    }
    if (act_x) {
#pragma unroll
      for (int r = 0; r < 4; ++r) {
        const float m = 1.0f - dcur[r];
        c[r] *= m;
        const int row = row0 + r;
        const int sl  = (uu >> 3) ^ row;
        hbuf[p ^ 1][row * U_ + sl * 8 + (uu & 7)] = (short)cvt_pk_bf16(hn[r] * m, 0.f);
      }
    }
    sync_lds();
  };

  for (int t = 0; t < T_; t += 2) {
    step(0, true, t + 2 < T_, accA, accB);
    Xt += B_ * F_; DNt += B_; Ot += B_ * U_;
    step(1, t + 2 < T_, t + 3 < T_, accB, accA);
    Xt += B_ * F_; DNt += B_; Ot += B_ * U_;
  }

  const long fb = (long)T_ * B_ * U_;
#pragma unroll
  for (int r = 0; r < 4; ++r) {
    OUT[fb + (long)(b0 + row0 + r) * U_ + uu]                 = c[r];
    OUT[fb + (long)B_ * U_ + (long)(b0 + row0 + r) * U_ + uu] = hn[r];
  }
}

extern "C" void kernel_launch(void* const* d_in, const int* in_sizes, int n_in,
                              void* d_out, int out_size, void* d_ws, size_t ws_size,
                              hipStream_t stream) {
  const float* X  = (const float*)d_in[0];  // [T,B,F]
  const float* ST = (const float*)d_in[1];  // [2,B,U]
  const float* DN = (const float*)d_in[2];  // [T,B]
  const float* WX = (const float*)d_in[3];  // [F,4U]
  const float* WH = (const float*)d_in[4];  // [U,4U]
  float* OUT = (float*)d_out;               // [T*B*U + 2*B*U]

  if (ws_size >= ZB_BYTES) {
    unsigned* ZB = (unsigned*)d_ws;
    zxb_gemm_kernel<<<dim3(512), dim3(512), 0, stream>>>(X, WX, ZB);
    lstm_zxb4_kernel<<<dim3(NBLK), dim3(512), 0, stream>>>(ZB, ST, DN, WH, OUT);
  } else {
    lstm_fb_kernel<<<dim3(16), dim3(512), 0, stream>>>(X, ST, DN, WX, WH, OUT);
  }
}